// Round 1
// baseline (416.185 us; speedup 1.0000x reference)
//
#include <hip/hip_runtime.h>
#include <hip/hip_bf16.h>

#define B_ 4
#define T_ 8192
#define N_ 64
#define F_ 16
#define O_ 32

typedef _Float16 half8_t __attribute__((ext_vector_type(8)));
typedef float float4_t __attribute__((ext_vector_type(4)));

// ---------------- workspace layout (byte offsets) ----------------
// A1   : 0        (4096 f32)    [b][n][f]   -- must be zeroed (atomics)
// G    : 16384    (4096 f32)    [b][m][f]
// Ssc  : 32768    (16384 f32)   [b][m][n]   S[b,m,n]*diag(adj)[n]
// Wft  : 98304    (393216 f16)  [b][o][K]   K = k*1024 + m*16 + f
// rhs  : 884736   (2097152 f32) [b][n][t]
#define WS_A1   0
#define WS_G    16384
#define WS_SSC  32768
#define WS_WFT  98304
#define WS_RHS  884736

// ---------------------------------------------------------------------------
// Kernel A: one pass over x. Computes
//   rhs[b,n,t] = sum_f W3[f] * x[b,t,n*16+f]
//   A1[b,n,f] += W1[t] * x[b,t,n*16+f]       (atomic across t-tiles)
// grid = B * (T/32) blocks of 256 threads; each block does 32 t-rows.
__global__ __launch_bounds__(256) void kA(const float* __restrict__ x,
                                          const float* __restrict__ W1,
                                          const float* __restrict__ W3,
                                          float* __restrict__ A1,
                                          float* __restrict__ rhs) {
    __shared__ float ldsr[64][33];  // [n][r], padded to kill bank conflicts
    const int b   = blockIdx.x >> 8;       // 256 tiles per b
    const int t0  = (blockIdx.x & 255) * 32;
    const int tid = threadIdx.x;
    const int n   = tid >> 2;              // vertex
    const int fq  = tid & 3;               // f-quarter (4 floats each)

    float w3v[4];
#pragma unroll
    for (int j = 0; j < 4; ++j) w3v[j] = W3[fq * 4 + j];

    const float* xbase = x + ((size_t)b * T_) * 1024 + tid * 4;
    float accA[4] = {0.f, 0.f, 0.f, 0.f};

    for (int r = 0; r < 32; ++r) {
        const int t = t0 + r;
        float4_t xv = *(const float4_t*)(xbase + (size_t)t * 1024);
        const float w1 = W1[t];
        float v = xv[0] * w3v[0] + xv[1] * w3v[1] + xv[2] * w3v[2] + xv[3] * w3v[3];
        v += __shfl_xor(v, 1);
        v += __shfl_xor(v, 2);
        if (fq == 0) ldsr[n][r] = v;
#pragma unroll
        for (int j = 0; j < 4; ++j) accA[j] += w1 * xv[j];
    }
#pragma unroll
    for (int j = 0; j < 4; ++j)
        atomicAdd(&A1[(b * 64 + n) * 16 + fq * 4 + j], accA[j]);

    __syncthreads();
    // coalesced rhs write-out: thread -> (n2, 8 consecutive t)
    const int n2 = tid >> 2;
    const int rb = (tid & 3) * 8;
    float4_t v0, v1;
#pragma unroll
    for (int j = 0; j < 4; ++j) { v0[j] = ldsr[n2][rb + j]; v1[j] = ldsr[n2][rb + 4 + j]; }
    float* rp = rhs + ((size_t)(b * 64 + n2)) * T_ + t0 + rb;
    *(float4_t*)(rp)     = v0;
    *(float4_t*)(rp + 4) = v1;
}

// ---------------------------------------------------------------------------
// Kernel B: G[b,m,f] = sum_t W2[f,t] * rhs[b,m,t].   grid = B*N blocks.
__global__ __launch_bounds__(256) void kB(const float* __restrict__ rhs,
                                          const float* __restrict__ W2,
                                          float* __restrict__ G) {
    const int b = blockIdx.x >> 6, m = blockIdx.x & 63;
    const float* rr = rhs + (size_t)(b * 64 + m) * T_;
    float acc[16];
#pragma unroll
    for (int f = 0; f < 16; ++f) acc[f] = 0.f;

    for (int t = threadIdx.x; t < T_; t += 256) {
        const float v = rr[t];
#pragma unroll
        for (int f = 0; f < 16; ++f) acc[f] += W2[f * T_ + t] * v;
    }
#pragma unroll
    for (int f = 0; f < 16; ++f)
        for (int off = 32; off; off >>= 1) acc[f] += __shfl_xor(acc[f], off);

    __shared__ float red[4][16];
    const int w = threadIdx.x >> 6, lane = threadIdx.x & 63;
    if (lane == 0) {
#pragma unroll
        for (int f = 0; f < 16; ++f) red[w][f] = acc[f];
    }
    __syncthreads();
    if (threadIdx.x < 16) {
        const int f = threadIdx.x;
        G[(b * 64 + m) * 16 + f] = red[0][f] + red[1][f] + red[2][f] + red[3][f];
    }
}

// ---------------------------------------------------------------------------
// Kernel C: per-b attention matrix.
//   product[r][c] = sum_f A1[b,r,f]*G[b,c,f];  sig = sigmoid(product + bs)
//   S0[r][c] = sum_m Vs[r,m]*sig[m][c];  S = softmax over r (axis=1)
//   Ssc[b][m][n] = S[m][n] * adj[n,n]
// grid = B blocks.
__global__ __launch_bounds__(256) void kC(const float* __restrict__ A1,
                                          const float* __restrict__ G,
                                          const float* __restrict__ bs,
                                          const float* __restrict__ Vs,
                                          const float* __restrict__ adj,
                                          float* __restrict__ Ssc) {
    const int b = blockIdx.x;
    __shared__ float a1[64][17], g[64][17];
    __shared__ float sig[64][64], s0[64][64];
    const int tid = threadIdx.x;

    for (int i = tid; i < 1024; i += 256) {
        a1[i >> 4][i & 15] = A1[b * 1024 + i];
        g [i >> 4][i & 15] = G [b * 1024 + i];
    }
    __syncthreads();

#pragma unroll
    for (int i = 0; i < 16; ++i) {
        const int e = tid + 256 * i, r = e >> 6, c = e & 63;
        float p = 0.f;
#pragma unroll
        for (int f = 0; f < 16; ++f) p += a1[r][f] * g[c][f];
        p += bs[e];
        sig[r][c] = 1.f / (1.f + __expf(-p));
    }
    __syncthreads();

#pragma unroll
    for (int i = 0; i < 16; ++i) {
        const int e = tid + 256 * i, r = e >> 6, c = e & 63;
        float s = 0.f;
        for (int m = 0; m < 64; ++m) s += Vs[r * 64 + m] * sig[m][c];
        s0[r][c] = s;
    }
    __syncthreads();

    if (tid < 64) {
        const int c = tid;
        float mx = -1e30f;
        for (int r = 0; r < 64; ++r) mx = fmaxf(mx, s0[r][c]);
        float sum = 0.f;
        for (int r = 0; r < 64; ++r) { const float ev = __expf(s0[r][c] - mx); s0[r][c] = ev; sum += ev; }
        const float inv = 1.f / sum;
        const float dg = adj[c * 64 + c];
        for (int r = 0; r < 64; ++r)
            Ssc[b * 4096 + r * 64 + c] = s0[r][c] * inv * dg;
    }
}

// ---------------------------------------------------------------------------
// Kernel D: fold conv weights through attention:
//   Wft[b][o][K] = sum_n conv_w[o, n*16+f, k] * Ssc[b][m][n],  K = k*1024+m*16+f
// grid = B*O blocks.
__global__ __launch_bounds__(256) void kD(const float* __restrict__ Ssc,
                                          const float* __restrict__ conv_w,
                                          _Float16* __restrict__ Wft) {
    const int b = blockIdx.x >> 5, o = blockIdx.x & 31;
    __shared__ float ssc[4096];
    __shared__ float cw[3072];
    const int tid = threadIdx.x;
    for (int i = tid; i < 4096; i += 256) ssc[i] = Ssc[b * 4096 + i];
    for (int i = tid; i < 3072; i += 256) cw[i] = conv_w[o * 3072 + i];
    __syncthreads();

#pragma unroll
    for (int i = 0; i < 12; ++i) {
        const int e = tid + 256 * i;
        const int k = e >> 10, rem = e & 1023, m = rem >> 4, f = rem & 15;
        float s = 0.f;
#pragma unroll
        for (int n = 0; n < 64; ++n) s += cw[(n * 16 + f) * 3 + k] * ssc[m * 64 + n];
        Wft[(size_t)(b * 32 + o) * 3072 + e] = (_Float16)s;
    }
}

// ---------------------------------------------------------------------------
// Kernel E: out[b,t,o] = sum_{K} x[b, t + K/1024 - 1, K%1024] * Wft[b][o][K]
// f16 MFMA 16x16x32. Wave tile: 16 t x 32 o. Block = 4 waves = 64 t.
// grid = B * (T/64) = 512 blocks.
__global__ __launch_bounds__(256) void kE(const float* __restrict__ x,
                                          const _Float16* __restrict__ Wft,
                                          float* __restrict__ out) {
    const int b    = blockIdx.x >> 7;
    const int tile = blockIdx.x & 127;
    const int wave = threadIdx.x >> 6;
    const int lane = threadIdx.x & 63;
    const int q = lane >> 4, l = lane & 15;
    const int t0 = tile * 64 + wave * 16;

    const _Float16* wb0 = Wft + (size_t)(b * 32 + l) * 3072;  // o = l
    const _Float16* wb1 = wb0 + 16 * 3072;                    // o = 16 + l
    const float* xb = x + (size_t)b * T_ * 1024;

    float4_t acc0 = {0.f, 0.f, 0.f, 0.f};
    float4_t acc1 = {0.f, 0.f, 0.f, 0.f};

#pragma unroll 4
    for (int kk = 0; kk < 96; ++kk) {
        const int K  = kk * 32;
        const int kc = K >> 10;                // conv tap 0..2
        const int c0 = (K & 1023) + q * 8;     // channel
        const int row = t0 + l + kc - 1;       // t index into x (may be OOB)
        const bool valid = (unsigned)row < (unsigned)T_;
        const int rc = valid ? row : 0;
        const float sc = valid ? 1.f : 0.f;

        const float* ap = xb + (size_t)rc * 1024 + c0;
        float4_t a0 = *(const float4_t*)ap;
        float4_t a1 = *(const float4_t*)(ap + 4);

        half8_t af;
        af[0] = (_Float16)(a0[0] * sc); af[1] = (_Float16)(a0[1] * sc);
        af[2] = (_Float16)(a0[2] * sc); af[3] = (_Float16)(a0[3] * sc);
        af[4] = (_Float16)(a1[0] * sc); af[5] = (_Float16)(a1[1] * sc);
        af[6] = (_Float16)(a1[2] * sc); af[7] = (_Float16)(a1[3] * sc);

        half8_t bf0 = *(const half8_t*)(wb0 + K + q * 8);
        half8_t bf1 = *(const half8_t*)(wb1 + K + q * 8);

        acc0 = __builtin_amdgcn_mfma_f32_16x16x32_f16(af, bf0, acc0, 0, 0, 0);
        acc1 = __builtin_amdgcn_mfma_f32_16x16x32_f16(af, bf1, acc1, 0, 0, 0);
    }

#pragma unroll
    for (int rg = 0; rg < 4; ++rg) {
        const int t = t0 + q * 4 + rg;
        float* op = out + ((size_t)b * T_ + t) * 32;
        op[l]      = acc0[rg];
        op[16 + l] = acc1[rg];
    }
}

// ---------------------------------------------------------------------------
extern "C" void kernel_launch(void* const* d_in, const int* in_sizes, int n_in,
                              void* d_out, int out_size, void* d_ws, size_t ws_size,
                              hipStream_t stream) {
    const float* x      = (const float*)d_in[0];
    const float* adj    = (const float*)d_in[1];
    const float* W1     = (const float*)d_in[2];
    const float* W2     = (const float*)d_in[3];
    const float* W3     = (const float*)d_in[4];
    const float* bs     = (const float*)d_in[5];
    const float* Vs     = (const float*)d_in[6];
    const float* conv_w = (const float*)d_in[7];
    float* out = (float*)d_out;

    char* ws = (char*)d_ws;
    float*    A1  = (float*)(ws + WS_A1);
    float*    G   = (float*)(ws + WS_G);
    float*    Ssc = (float*)(ws + WS_SSC);
    _Float16* Wft = (_Float16*)(ws + WS_WFT);
    float*    rhs = (float*)(ws + WS_RHS);

    // A1 is accumulated with atomics -> zero it (ws is poisoned each call)
    hipMemsetAsync(A1, 0, 4096 * sizeof(float), stream);

    kA<<<B_ * (T_ / 32), 256, 0, stream>>>(x, W1, W3, A1, rhs);
    kB<<<B_ * N_,        256, 0, stream>>>(rhs, W2, G);
    kC<<<B_,             256, 0, stream>>>(A1, G, bs, Vs, adj, Ssc);
    kD<<<B_ * O_,        256, 0, stream>>>(Ssc, conv_w, Wft);
    kE<<<B_ * (T_ / 64), 256, 0, stream>>>(x, Wft, out);
}